// Round 1
// baseline (684.891 us; speedup 1.0000x reference)
//
#include <hip/hip_runtime.h>
#include <hip/hip_bf16.h>
#include <cfloat>

#define HD 128

// -------- Kernel 1: segment bounds (batch is sorted) --------
__global__ void seg_bounds_kernel(const int* __restrict__ batch, int n, int nseg,
                                  int* __restrict__ seg_start) {
  int b = blockIdx.x * blockDim.x + threadIdx.x;
  if (b > nseg) return;
  if (b == nseg) { seg_start[b] = n; return; }
  int lo = 0, hi = n;
  while (lo < hi) {
    int mid = (lo + hi) >> 1;
    if (batch[mid] < b) lo = mid + 1; else hi = mid;
  }
  seg_start[b] = lo;
}

// -------- Kernel 2: per-node gate score = tanh(h@W1+b1)@w2 + b2 --------
// Block: 256 threads. Thread tile: 4 nodes x 8 cols. Block tile: 64 nodes x 128 cols.
// W1 (128x128 fp32, 64 KB) staged in LDS once per block; grid-stride over node tiles.
__global__ __launch_bounds__(256, 2) void score_kernel(
    const float* __restrict__ h, const float* __restrict__ w1,
    const float* __restrict__ b1, const float* __restrict__ w2,
    const float* __restrict__ b2, float* __restrict__ score, int nTiles)
{
  __shared__ float sW1[HD * HD];  // row-major [k][j], 64 KB
  for (int i = threadIdx.x; i < HD * HD / 4; i += 256)
    reinterpret_cast<float4*>(sW1)[i] = reinterpret_cast<const float4*>(w1)[i];
  __syncthreads();

  const int c  = threadIdx.x & 15;   // col-group: cols 8c..8c+7
  const int ng = threadIdx.x >> 4;   // node-group: nodes 4ng..4ng+3 within tile
  float w2r[8], b1r[8];
#pragma unroll
  for (int j = 0; j < 8; ++j) { w2r[j] = w2[8 * c + j]; b1r[j] = b1[8 * c + j]; }
  const float b2v = b2[0];

  for (int tile = blockIdx.x; tile < nTiles; tile += gridDim.x) {
    const size_t nodeBase = (size_t)tile * 64 + (size_t)ng * 4;
    const float* hp = h + nodeBase * HD;
    float acc[4][8];
#pragma unroll
    for (int i = 0; i < 4; ++i)
#pragma unroll
      for (int j = 0; j < 8; ++j) acc[i][j] = 0.f;

    for (int kq = 0; kq < HD / 4; ++kq) {
      float4 hv[4];
#pragma unroll
      for (int i = 0; i < 4; ++i)
        hv[i] = *reinterpret_cast<const float4*>(hp + (size_t)i * HD + kq * 4);
#pragma unroll
      for (int kk = 0; kk < 4; ++kk) {
        const int k = kq * 4 + kk;
        const float4 wa = *reinterpret_cast<const float4*>(&sW1[k * HD + 8 * c]);
        const float4 wb = *reinterpret_cast<const float4*>(&sW1[k * HD + 8 * c + 4]);
        const float w[8] = {wa.x, wa.y, wa.z, wa.w, wb.x, wb.y, wb.z, wb.w};
        float hk[4];
#pragma unroll
        for (int i = 0; i < 4; ++i)
          hk[i] = reinterpret_cast<const float*>(&hv[i])[kk];
#pragma unroll
        for (int i = 0; i < 4; ++i)
#pragma unroll
          for (int j = 0; j < 8; ++j)
            acc[i][j] = fmaf(hk[i], w[j], acc[i][j]);
      }
    }

    // tanh + dot with w2 slice
    float p[4] = {0.f, 0.f, 0.f, 0.f};
#pragma unroll
    for (int i = 0; i < 4; ++i) {
#pragma unroll
      for (int j = 0; j < 8; ++j) {
        float x = acc[i][j] + b1r[j];
        x = fminf(fmaxf(x, -15.f), 15.f);          // tanh(+-15)==+-1 in fp32
        float t = __expf(2.f * x);                  // e^{2x}
        float th = 1.f - __fdividef(2.f, t + 1.f);  // tanh(x)
        p[i] = fmaf(th, w2r[j], p[i]);
      }
    }
    // reduce across the 16 col-groups (contiguous 16-lane clusters)
#pragma unroll
    for (int i = 0; i < 4; ++i) {
      p[i] += __shfl_xor(p[i], 1, 16);
      p[i] += __shfl_xor(p[i], 2, 16);
      p[i] += __shfl_xor(p[i], 4, 16);
      p[i] += __shfl_xor(p[i], 8, 16);
    }
    if (c == 0) {
#pragma unroll
      for (int i = 0; i < 4; ++i) score[nodeBase + i] = p[i] + b2v;
    }
  }
}

// -------- Kernel 3: per-segment softmax stats + attention/max pooling --------
// One block (128 threads) per segment. Thread t owns feature t.
__global__ __launch_bounds__(128) void pool_kernel(
    const float* __restrict__ h, const float* __restrict__ score,
    const int* __restrict__ seg_start, float* __restrict__ g)
{
  const int b = blockIdx.x;
  const int t = threadIdx.x;
  const int s0 = seg_start[b];
  const int s1 = seg_start[b + 1];
  const int len = s1 - s0;

  __shared__ float sred[2];
  __shared__ float sattn[128];

  // A1: segment max of score
  float mx = -FLT_MAX;
  for (int i = t; i < len; i += 128) mx = fmaxf(mx, score[s0 + i]);
#pragma unroll
  for (int off = 32; off >= 1; off >>= 1) mx = fmaxf(mx, __shfl_xor(mx, off, 64));
  if ((t & 63) == 0) sred[t >> 6] = mx;
  __syncthreads();
  mx = fmaxf(sred[0], sred[1]);
  __syncthreads();

  // A2: sum of exp
  float se = 0.f;
  for (int i = t; i < len; i += 128) se += __expf(score[s0 + i] - mx);
#pragma unroll
  for (int off = 32; off >= 1; off >>= 1) se += __shfl_xor(se, off, 64);
  if ((t & 63) == 0) sred[t >> 6] = se;
  __syncthreads();
  se = sred[0] + sred[1];
  const float inv = 1.f / se;

  // B: feature-parallel accumulation, nodes in chunks of 128
  float ga = 0.f, gm = -FLT_MAX;
  for (int base = 0; base < len; base += 128) {
    __syncthreads();
    const int m = min(128, len - base);
    if (t < m) sattn[t] = __expf(score[s0 + base + t] - mx) * inv;
    __syncthreads();
    const float* hp = h + (size_t)(s0 + base) * HD + t;
#pragma unroll 4
    for (int nn = 0; nn < m; ++nn) {
      float hv = hp[(size_t)nn * HD];
      ga = fmaf(hv, sattn[nn], ga);
      gm = fmaxf(gm, hv);
    }
  }
  g[(size_t)b * 256 + t] = ga;          // g_attn
  g[(size_t)b * 256 + 128 + t] = gm;    // g_max (concat order matches reference)
}

// -------- Kernel 4: MLP head: relu(g@W1m+b1m)@w2m + b2m --------
__global__ __launch_bounds__(128) void mlp_kernel(
    const float* __restrict__ g, const float* __restrict__ w1,
    const float* __restrict__ b1, const float* __restrict__ w2,
    const float* __restrict__ b2, float* __restrict__ out)
{
  __shared__ float sg[256];
  __shared__ float sred[2];
  const int b = blockIdx.x;
  const int t = threadIdx.x;
  sg[t] = g[(size_t)b * 256 + t];
  sg[t + 128] = g[(size_t)b * 256 + 128 + t];
  __syncthreads();
  float acc = b1[t];
#pragma unroll 8
  for (int k = 0; k < 256; ++k)
    acc = fmaf(sg[k], w1[k * HD + t], acc);
  float hid = fmaxf(acc, 0.f);
  float v = hid * w2[t];
#pragma unroll
  for (int off = 32; off >= 1; off >>= 1) v += __shfl_xor(v, off, 64);
  if ((t & 63) == 0) sred[t >> 6] = v;
  __syncthreads();
  if (t == 0) out[b] = sred[0] + sred[1] + b2[0];
}

extern "C" void kernel_launch(void* const* d_in, const int* in_sizes, int n_in,
                              void* d_out, int out_size, void* d_ws, size_t ws_size,
                              hipStream_t stream) {
  const float* h       = (const float*)d_in[0];
  const int*   batch   = (const int*)d_in[1];
  const float* gate_w1 = (const float*)d_in[2];
  const float* gate_b1 = (const float*)d_in[3];
  const float* gate_w2 = (const float*)d_in[4];
  const float* gate_b2 = (const float*)d_in[5];
  const float* mlp_w1  = (const float*)d_in[6];
  const float* mlp_b1  = (const float*)d_in[7];
  const float* mlp_w2  = (const float*)d_in[8];
  const float* mlp_b2  = (const float*)d_in[9];
  float* out = (float*)d_out;

  const int N = in_sizes[0] / HD;   // 1048576
  const int B = out_size;           // 4096 (NUM_OBS == 1)

  char* ws = (char*)d_ws;
  float* score = (float*)ws;                                        // N floats
  float* g     = (float*)(ws + (size_t)N * 4);                      // B*256 floats
  int*   seg   = (int*)(ws + (size_t)N * 4 + (size_t)B * 256 * 4);  // B+1 ints

  seg_bounds_kernel<<<(B + 256) / 256, 256, 0, stream>>>(batch, N, B, seg);
  score_kernel<<<1024, 256, 0, stream>>>(h, gate_w1, gate_b1, gate_w2, gate_b2,
                                         score, N / 64);
  pool_kernel<<<B, 128, 0, stream>>>(h, score, seg, g);
  mlp_kernel<<<B, 128, 0, stream>>>(g, mlp_w1, mlp_b1, mlp_w2, mlp_b2, out);
}

// Round 2
// 303.260 us; speedup vs baseline: 2.2584x; 2.2584x over previous
//
#include <hip/hip_runtime.h>
#include <hip/hip_bf16.h>
#include <cfloat>

#define HD 128

typedef float f32x4 __attribute__((ext_vector_type(4)));
typedef __bf16 bf16x8 __attribute__((ext_vector_type(8)));

// -------- Kernel 1: segment bounds (batch is sorted) --------
__global__ void seg_bounds_kernel(const int* __restrict__ batch, int n, int nseg,
                                  int* __restrict__ seg_start) {
  int b = blockIdx.x * blockDim.x + threadIdx.x;
  if (b > nseg) return;
  if (b == nseg) { seg_start[b] = n; return; }
  int lo = 0, hi = n;
  while (lo < hi) {
    int mid = (lo + hi) >> 1;
    if (batch[mid] < b) lo = mid + 1; else hi = mid;
  }
  seg_start[b] = lo;
}

// -------- Kernel 2: gate score via bf16 MFMA --------
// score[n] = tanh(h[n,:] @ W1 + b1) @ w2 + b2
// Wave-level: 16-node tiles. B-operand (full 128x128 W1, bf16) held in
// registers per lane (32 frags x 4 VGPR = 128 VGPR), gathered once from a
// transposed LDS staging buffer. Steady-state loop: global h loads -> cvt ->
// 32 MFMA -> tanh epilogue. No LDS traffic in the loop.
__global__ __launch_bounds__(256, 2) void score_mfma_kernel(
    const float* __restrict__ h, const float* __restrict__ w1,
    const float* __restrict__ b1, const float* __restrict__ w2,
    const float* __restrict__ b2, float* __restrict__ score, int nTiles)
{
  __shared__ __bf16 sWt[HD * HD];  // transposed: sWt[c*128 + k], 32 KB

  // Cooperative stage: coalesced float4 reads of w1[k][c], scalar bf16 writes
  // to transposed LDS (one-time; write conflicts acceptable).
  for (int i = threadIdx.x; i < HD * HD / 4; i += 256) {
    const int k = i >> 5;          // row of w1
    const int c4 = (i & 31) << 2;  // starting col
    const float4 v = reinterpret_cast<const float4*>(w1)[i];
    sWt[(c4 + 0) * HD + k] = (__bf16)v.x;
    sWt[(c4 + 1) * HD + k] = (__bf16)v.y;
    sWt[(c4 + 2) * HD + k] = (__bf16)v.z;
    sWt[(c4 + 3) * HD + k] = (__bf16)v.w;
  }
  __syncthreads();

  const int lane = threadIdx.x & 63;
  const int wid  = threadIdx.x >> 6;
  const int lr   = lane & 15;   // fragment row/col index
  const int kl   = lane >> 4;   // k-subgroup: k = 8*kl + j

  // Gather B fragments: B[f][kt] covers cols 16f..16f+15, k = 32kt..32kt+31.
  // Lane holds W1[k = 32kt + 8kl + j][c = 16f + lr], j=0..7 -> contiguous in sWt.
  bf16x8 Bf[8][4];
#pragma unroll
  for (int f = 0; f < 8; ++f) {
#pragma unroll
    for (int kt = 0; kt < 4; ++kt) {
      Bf[f][kt] = *reinterpret_cast<const bf16x8*>(
          &sWt[(16 * f + lr) * HD + 32 * kt + 8 * kl]);
    }
  }

  // Per-lane epilogue constants: col c = 16f + lr for fragment f.
  float w2r[8], b1r[8];
#pragma unroll
  for (int f = 0; f < 8; ++f) { w2r[f] = w2[16 * f + lr]; b1r[f] = b1[16 * f + lr]; }
  const float b2v = b2[0];

  const int gw = blockIdx.x * 4 + wid;          // global wave id (4096 total)
  const int tilesPerWave = nTiles / (gridDim.x * 4);
  const int t0 = gw * tilesPerWave;

  for (int t = t0; t < t0 + tilesPerWave; ++t) {
    const size_t nodeBase = (size_t)t * 16;
    // A-operand: lane holds h[node = nodeBase + lr][k = 32kt + 8kl + j]
    const float* hp = h + (nodeBase + lr) * HD + 8 * kl;
    float4 hv[8];
#pragma unroll
    for (int kt = 0; kt < 4; ++kt) {
      hv[2 * kt + 0] = *reinterpret_cast<const float4*>(hp + 32 * kt);
      hv[2 * kt + 1] = *reinterpret_cast<const float4*>(hp + 32 * kt + 4);
    }
    bf16x8 a[4];
#pragma unroll
    for (int kt = 0; kt < 4; ++kt) {
      const float* pv = reinterpret_cast<const float*>(&hv[2 * kt]);
#pragma unroll
      for (int j = 0; j < 8; ++j) a[kt][j] = (__bf16)pv[j];
    }

    f32x4 acc[8];
#pragma unroll
    for (int f = 0; f < 8; ++f) acc[f] = (f32x4){0.f, 0.f, 0.f, 0.f};
#pragma unroll
    for (int kt = 0; kt < 4; ++kt)
#pragma unroll
      for (int f = 0; f < 8; ++f)
        acc[f] = __builtin_amdgcn_mfma_f32_16x16x32_bf16(a[kt], Bf[f][kt], acc[f], 0, 0, 0);

    // Epilogue: D-frag lane layout: col = 16f + lr, rows = 4*kl + r.
    float p[4] = {0.f, 0.f, 0.f, 0.f};
#pragma unroll
    for (int f = 0; f < 8; ++f) {
#pragma unroll
      for (int r = 0; r < 4; ++r) {
        float x = acc[f][r] + b1r[f];
        x = fminf(fmaxf(x, -15.f), 15.f);
        float e = __expf(2.f * x);
        float th = 1.f - __fdividef(2.f, e + 1.f);  // tanh(x)
        p[r] = fmaf(th, w2r[f], p[r]);
      }
    }
    // Reduce over the 16 cols held by lanes sharing kl (xor width 16).
#pragma unroll
    for (int r = 0; r < 4; ++r) {
      p[r] += __shfl_xor(p[r], 1, 16);
      p[r] += __shfl_xor(p[r], 2, 16);
      p[r] += __shfl_xor(p[r], 4, 16);
      p[r] += __shfl_xor(p[r], 8, 16);
    }
    if (lr == 0) {
#pragma unroll
      for (int r = 0; r < 4; ++r) score[nodeBase + 4 * kl + r] = p[r] + b2v;
    }
  }
}

// -------- Kernel 3: per-segment softmax stats + attention/max pooling --------
__global__ __launch_bounds__(128) void pool_kernel(
    const float* __restrict__ h, const float* __restrict__ score,
    const int* __restrict__ seg_start, float* __restrict__ g)
{
  const int b = blockIdx.x;
  const int t = threadIdx.x;
  const int s0 = seg_start[b];
  const int s1 = seg_start[b + 1];
  const int len = s1 - s0;

  __shared__ float sred[2];
  __shared__ float sattn[128];

  float mx = -FLT_MAX;
  for (int i = t; i < len; i += 128) mx = fmaxf(mx, score[s0 + i]);
#pragma unroll
  for (int off = 32; off >= 1; off >>= 1) mx = fmaxf(mx, __shfl_xor(mx, off, 64));
  if ((t & 63) == 0) sred[t >> 6] = mx;
  __syncthreads();
  mx = fmaxf(sred[0], sred[1]);
  __syncthreads();

  float se = 0.f;
  for (int i = t; i < len; i += 128) se += __expf(score[s0 + i] - mx);
#pragma unroll
  for (int off = 32; off >= 1; off >>= 1) se += __shfl_xor(se, off, 64);
  if ((t & 63) == 0) sred[t >> 6] = se;
  __syncthreads();
  se = sred[0] + sred[1];
  const float inv = 1.f / se;

  float ga = 0.f, gm = -FLT_MAX;
  for (int base = 0; base < len; base += 128) {
    __syncthreads();
    const int m = min(128, len - base);
    if (t < m) sattn[t] = __expf(score[s0 + base + t] - mx) * inv;
    __syncthreads();
    const float* hp = h + (size_t)(s0 + base) * HD + t;
#pragma unroll 4
    for (int nn = 0; nn < m; ++nn) {
      float hv = hp[(size_t)nn * HD];
      ga = fmaf(hv, sattn[nn], ga);
      gm = fmaxf(gm, hv);
    }
  }
  g[(size_t)b * 256 + t] = ga;
  g[(size_t)b * 256 + 128 + t] = gm;
}

// -------- Kernel 4: MLP head --------
__global__ __launch_bounds__(128) void mlp_kernel(
    const float* __restrict__ g, const float* __restrict__ w1,
    const float* __restrict__ b1, const float* __restrict__ w2,
    const float* __restrict__ b2, float* __restrict__ out)
{
  __shared__ float sg[256];
  __shared__ float sred[2];
  const int b = blockIdx.x;
  const int t = threadIdx.x;
  sg[t] = g[(size_t)b * 256 + t];
  sg[t + 128] = g[(size_t)b * 256 + 128 + t];
  __syncthreads();
  float acc = b1[t];
#pragma unroll 8
  for (int k = 0; k < 256; ++k)
    acc = fmaf(sg[k], w1[k * HD + t], acc);
  float hid = fmaxf(acc, 0.f);
  float v = hid * w2[t];
#pragma unroll
  for (int off = 32; off >= 1; off >>= 1) v += __shfl_xor(v, off, 64);
  if ((t & 63) == 0) sred[t >> 6] = v;
  __syncthreads();
  if (t == 0) out[b] = sred[0] + sred[1] + b2[0];
}

extern "C" void kernel_launch(void* const* d_in, const int* in_sizes, int n_in,
                              void* d_out, int out_size, void* d_ws, size_t ws_size,
                              hipStream_t stream) {
  const float* h       = (const float*)d_in[0];
  const int*   batch   = (const int*)d_in[1];
  const float* gate_w1 = (const float*)d_in[2];
  const float* gate_b1 = (const float*)d_in[3];
  const float* gate_w2 = (const float*)d_in[4];
  const float* gate_b2 = (const float*)d_in[5];
  const float* mlp_w1  = (const float*)d_in[6];
  const float* mlp_b1  = (const float*)d_in[7];
  const float* mlp_w2  = (const float*)d_in[8];
  const float* mlp_b2  = (const float*)d_in[9];
  float* out = (float*)d_out;

  const int N = in_sizes[0] / HD;   // 1048576
  const int B = out_size;           // 4096

  char* ws = (char*)d_ws;
  float* score = (float*)ws;                                        // N floats
  float* g     = (float*)(ws + (size_t)N * 4);                      // B*256 floats
  int*   seg   = (int*)(ws + (size_t)N * 4 + (size_t)B * 256 * 4);  // B+1 ints

  seg_bounds_kernel<<<(B + 256) / 256, 256, 0, stream>>>(batch, N, B, seg);
  // 1024 blocks x 4 waves = 4096 waves; 65536 tiles -> 16 tiles/wave.
  score_mfma_kernel<<<1024, 256, 0, stream>>>(h, gate_w1, gate_b1, gate_w2,
                                              gate_b2, score, N / 16);
  pool_kernel<<<B, 128, 0, stream>>>(h, score, seg, g);
  mlp_kernel<<<B, 128, 0, stream>>>(g, mlp_w1, mlp_b1, mlp_w2, mlp_b2, out);
}

// Round 3
// 275.056 us; speedup vs baseline: 2.4900x; 1.1025x over previous
//
#include <hip/hip_runtime.h>
#include <hip/hip_bf16.h>
#include <cfloat>

#define HD 128

typedef float f32x4 __attribute__((ext_vector_type(4)));
typedef __bf16 bf16x8 __attribute__((ext_vector_type(8)));

// -------- Kernel 1: segment bounds (batch is sorted) --------
__global__ void seg_bounds_kernel(const int* __restrict__ batch, int n, int nseg,
                                  int* __restrict__ seg_start) {
  int b = blockIdx.x * blockDim.x + threadIdx.x;
  if (b > nseg) return;
  if (b == nseg) { seg_start[b] = n; return; }
  int lo = 0, hi = n;
  while (lo < hi) {
    int mid = (lo + hi) >> 1;
    if (batch[mid] < b) lo = mid + 1; else hi = mid;
  }
  seg_start[b] = lo;
}

// -------- Kernel 2: gate score via bf16 MFMA, software-pipelined --------
// score[n] = tanh(h[n,:] @ W1 + b1) @ w2 + b2
// Full W1 (bf16) in registers per lane (32 frags x 4 VGPR). Loop: issue next
// tile's global loads BEFORE this tile's MFMA+epilogue so HBM latency hides
// under ~500 cycles of compute.
__global__ __launch_bounds__(256, 2) void score_mfma_kernel(
    const float* __restrict__ h, const float* __restrict__ w1,
    const float* __restrict__ b1, const float* __restrict__ w2,
    const float* __restrict__ b2, float* __restrict__ score, int nTiles)
{
  __shared__ __bf16 sWt[HD * HD];  // transposed: sWt[c*128 + k], 32 KB

  for (int i = threadIdx.x; i < HD * HD / 4; i += 256) {
    const int k = i >> 5;
    const int c4 = (i & 31) << 2;
    const float4 v = reinterpret_cast<const float4*>(w1)[i];
    sWt[(c4 + 0) * HD + k] = (__bf16)v.x;
    sWt[(c4 + 1) * HD + k] = (__bf16)v.y;
    sWt[(c4 + 2) * HD + k] = (__bf16)v.z;
    sWt[(c4 + 3) * HD + k] = (__bf16)v.w;
  }
  __syncthreads();

  const int lane = threadIdx.x & 63;
  const int wid  = threadIdx.x >> 6;
  const int lr   = lane & 15;   // fragment row/col index
  const int kl   = lane >> 4;   // k-subgroup

  bf16x8 Bf[8][4];
#pragma unroll
  for (int f = 0; f < 8; ++f)
#pragma unroll
    for (int kt = 0; kt < 4; ++kt)
      Bf[f][kt] = *reinterpret_cast<const bf16x8*>(
          &sWt[(16 * f + lr) * HD + 32 * kt + 8 * kl]);

  float w2r[8], b1r[8];
#pragma unroll
  for (int f = 0; f < 8; ++f) { w2r[f] = w2[16 * f + lr]; b1r[f] = b1[16 * f + lr]; }
  const float b2v = b2[0];

  const int gw = blockIdx.x * 4 + wid;
  const int tilesPerWave = nTiles / (gridDim.x * 4);
  const int t0 = gw * tilesPerWave;
  const int tEnd = t0 + tilesPerWave;

  // Prologue: load + cvt tile t0.
  bf16x8 a[4];
  {
    const float* hp = h + ((size_t)t0 * 16 + lr) * HD + 8 * kl;
#pragma unroll
    for (int kt = 0; kt < 4; ++kt) {
      float4 v0 = *reinterpret_cast<const float4*>(hp + 32 * kt);
      float4 v1 = *reinterpret_cast<const float4*>(hp + 32 * kt + 4);
      const float pv[8] = {v0.x, v0.y, v0.z, v0.w, v1.x, v1.y, v1.z, v1.w};
#pragma unroll
      for (int j = 0; j < 8; ++j) a[kt][j] = (__bf16)pv[j];
    }
  }

  for (int t = t0; t < tEnd; ++t) {
    const bool hasNext = (t + 1 < tEnd);
    float4 hv[8];
    if (hasNext) {
      const float* hp = h + ((size_t)(t + 1) * 16 + lr) * HD + 8 * kl;
#pragma unroll
      for (int kt = 0; kt < 4; ++kt) {
        hv[2 * kt + 0] = *reinterpret_cast<const float4*>(hp + 32 * kt);
        hv[2 * kt + 1] = *reinterpret_cast<const float4*>(hp + 32 * kt + 4);
      }
    }

    f32x4 acc[8];
#pragma unroll
    for (int f = 0; f < 8; ++f) acc[f] = (f32x4){0.f, 0.f, 0.f, 0.f};
#pragma unroll
    for (int kt = 0; kt < 4; ++kt)
#pragma unroll
      for (int f = 0; f < 8; ++f)
        acc[f] = __builtin_amdgcn_mfma_f32_16x16x32_bf16(a[kt], Bf[f][kt], acc[f], 0, 0, 0);

    // Epilogue: D layout col = 16f + lr, row = 4*kl + r.
    const size_t nodeBase = (size_t)t * 16;
    float p[4] = {0.f, 0.f, 0.f, 0.f};
#pragma unroll
    for (int f = 0; f < 8; ++f) {
#pragma unroll
      for (int r = 0; r < 4; ++r) {
        float x = acc[f][r] + b1r[f];
        float e = __expf(2.f * x);                  // saturates correctly
        float th = 1.f - __fdividef(2.f, e + 1.f);  // tanh(x)
        p[r] = fmaf(th, w2r[f], p[r]);
      }
    }
#pragma unroll
    for (int r = 0; r < 4; ++r) {
      p[r] += __shfl_xor(p[r], 1, 16);
      p[r] += __shfl_xor(p[r], 2, 16);
      p[r] += __shfl_xor(p[r], 4, 16);
      p[r] += __shfl_xor(p[r], 8, 16);
    }
    if (lr == 0) {
#pragma unroll
      for (int r = 0; r < 4; ++r) score[nodeBase + 4 * kl + r] = p[r] + b2v;
    }

    if (hasNext) {
#pragma unroll
      for (int kt = 0; kt < 4; ++kt) {
        const float* pv = reinterpret_cast<const float*>(&hv[2 * kt]);
#pragma unroll
        for (int j = 0; j < 8; ++j) a[kt][j] = (__bf16)pv[j];
      }
    }
  }
}

// -------- Kernel 3: softmax stats + attention/max pooling (float4) --------
// 256 threads per segment: rg = t>>5 owns rows sub==rg (mod 8),
// c = t&31 owns features 4c..4c+3. Partials reduced through LDS.
#define NCH 64
__global__ __launch_bounds__(256) void pool_kernel(
    const float* __restrict__ h, const float* __restrict__ score,
    const int* __restrict__ seg_start, float* __restrict__ g)
{
  const int b = blockIdx.x;
  const int t = threadIdx.x;
  const int s0 = seg_start[b];
  const int len = seg_start[b + 1] - s0;

  __shared__ float swave[4];
  __shared__ float sattn[NCH];
  __shared__ float rga[8][128];
  __shared__ float rgm[8][128];

  // Phase A1: segment max of score
  float mx = -FLT_MAX;
  for (int i = t; i < len; i += 256) mx = fmaxf(mx, score[s0 + i]);
#pragma unroll
  for (int off = 32; off >= 1; off >>= 1) mx = fmaxf(mx, __shfl_xor(mx, off, 64));
  if ((t & 63) == 0) swave[t >> 6] = mx;
  __syncthreads();
  mx = fmaxf(fmaxf(swave[0], swave[1]), fmaxf(swave[2], swave[3]));
  __syncthreads();

  // Phase A2: sum of exp
  float se = 0.f;
  for (int i = t; i < len; i += 256) se += __expf(score[s0 + i] - mx);
#pragma unroll
  for (int off = 32; off >= 1; off >>= 1) se += __shfl_xor(se, off, 64);
  if ((t & 63) == 0) swave[t >> 6] = se;
  __syncthreads();
  se = swave[0] + swave[1] + swave[2] + swave[3];
  const float inv = 1.f / se;

  const int rg = t >> 5;
  const int c  = t & 31;
  float4 ga = {0.f, 0.f, 0.f, 0.f};
  float4 gm = {-FLT_MAX, -FLT_MAX, -FLT_MAX, -FLT_MAX};

  for (int base = 0; base < len; base += NCH) {
    __syncthreads();
    if (t < NCH) {
      const int r = base + t;
      sattn[t] = (r < len) ? __expf(score[s0 + r] - mx) * inv : 0.f;
    }
    __syncthreads();
    const int m = min(NCH, len - base);
#pragma unroll 4
    for (int sub = rg; sub < m; sub += 8) {
      const float4 hv = *reinterpret_cast<const float4*>(
          h + (size_t)(s0 + base + sub) * HD + 4 * c);
      const float w = sattn[sub];
      ga.x = fmaf(hv.x, w, ga.x); ga.y = fmaf(hv.y, w, ga.y);
      ga.z = fmaf(hv.z, w, ga.z); ga.w = fmaf(hv.w, w, ga.w);
      gm.x = fmaxf(gm.x, hv.x); gm.y = fmaxf(gm.y, hv.y);
      gm.z = fmaxf(gm.z, hv.z); gm.w = fmaxf(gm.w, hv.w);
    }
  }

  *reinterpret_cast<float4*>(&rga[rg][4 * c]) = ga;
  *reinterpret_cast<float4*>(&rgm[rg][4 * c]) = gm;
  __syncthreads();
#pragma unroll
  for (int off = 4; off >= 1; off >>= 1) {
    if (rg < off) {
      float4 a0 = *reinterpret_cast<float4*>(&rga[rg][4 * c]);
      const float4 a1 = *reinterpret_cast<const float4*>(&rga[rg + off][4 * c]);
      a0.x += a1.x; a0.y += a1.y; a0.z += a1.z; a0.w += a1.w;
      *reinterpret_cast<float4*>(&rga[rg][4 * c]) = a0;
      float4 m0 = *reinterpret_cast<float4*>(&rgm[rg][4 * c]);
      const float4 m1 = *reinterpret_cast<const float4*>(&rgm[rg + off][4 * c]);
      m0.x = fmaxf(m0.x, m1.x); m0.y = fmaxf(m0.y, m1.y);
      m0.z = fmaxf(m0.z, m1.z); m0.w = fmaxf(m0.w, m1.w);
      *reinterpret_cast<float4*>(&rgm[rg][4 * c]) = m0;
    }
    __syncthreads();
  }
  if (t < 128) {
    g[(size_t)b * 256 + t] = rga[0][t];
    g[(size_t)b * 256 + 128 + t] = rgm[0][t];
  }
}

// -------- Kernel 4: MLP head, 4 segments per block --------
__global__ __launch_bounds__(512) void mlp_kernel(
    const float* __restrict__ g, const float* __restrict__ w1,
    const float* __restrict__ b1, const float* __restrict__ w2,
    const float* __restrict__ b2, float* __restrict__ out)
{
  __shared__ float sg[4][256];
  __shared__ float sred[4][2];
  const int t = threadIdx.x;      // 0..511
  const int sidx = t >> 7;        // segment slot 0..3
  const int u = t & 127;          // hidden unit
  const int b0 = blockIdx.x * 4;
  sg[sidx][u]       = g[(size_t)(b0 + sidx) * 256 + u];
  sg[sidx][u + 128] = g[(size_t)(b0 + sidx) * 256 + 128 + u];
  __syncthreads();
  float acc = b1[u];
#pragma unroll 8
  for (int k = 0; k < 256; ++k)
    acc = fmaf(sg[sidx][k], w1[k * HD + u], acc);
  float v = fmaxf(acc, 0.f) * w2[u];
#pragma unroll
  for (int off = 32; off >= 1; off >>= 1) v += __shfl_xor(v, off, 64);
  if ((t & 63) == 0) sred[sidx][(t >> 6) & 1] = v;
  __syncthreads();
  if (u == 0) out[b0 + sidx] = sred[sidx][0] + sred[sidx][1] + b2[0];
}

extern "C" void kernel_launch(void* const* d_in, const int* in_sizes, int n_in,
                              void* d_out, int out_size, void* d_ws, size_t ws_size,
                              hipStream_t stream) {
  const float* h       = (const float*)d_in[0];
  const int*   batch   = (const int*)d_in[1];
  const float* gate_w1 = (const float*)d_in[2];
  const float* gate_b1 = (const float*)d_in[3];
  const float* gate_w2 = (const float*)d_in[4];
  const float* gate_b2 = (const float*)d_in[5];
  const float* mlp_w1  = (const float*)d_in[6];
  const float* mlp_b1  = (const float*)d_in[7];
  const float* mlp_w2  = (const float*)d_in[8];
  const float* mlp_b2  = (const float*)d_in[9];
  float* out = (float*)d_out;

  const int N = in_sizes[0] / HD;   // 1048576
  const int B = out_size;           // 4096

  char* ws = (char*)d_ws;
  float* score = (float*)ws;                                        // N floats
  float* g     = (float*)(ws + (size_t)N * 4);                      // B*256 floats
  int*   seg   = (int*)(ws + (size_t)N * 4 + (size_t)B * 256 * 4);  // B+1 ints

  seg_bounds_kernel<<<(B + 256) / 256, 256, 0, stream>>>(batch, N, B, seg);
  score_mfma_kernel<<<1024, 256, 0, stream>>>(h, gate_w1, gate_b1, gate_w2,
                                              gate_b2, score, N / 16);
  pool_kernel<<<B, 256, 0, stream>>>(h, score, seg, g);
  mlp_kernel<<<B / 4, 512, 0, stream>>>(g, mlp_w1, mlp_b1, mlp_w2, mlp_b2, out);
}

// Round 4
// 241.147 us; speedup vs baseline: 2.8401x; 1.1406x over previous
//
#include <hip/hip_runtime.h>
#include <hip/hip_bf16.h>
#include <cfloat>

#define HD 128

typedef float f32x4 __attribute__((ext_vector_type(4)));
typedef __bf16 bf16x8 __attribute__((ext_vector_type(8)));

// -------- Kernel 1: segment bounds (batch is sorted) --------
__global__ void seg_bounds_kernel(const int* __restrict__ batch, int n, int nseg,
                                  int* __restrict__ seg_start) {
  int b = blockIdx.x * blockDim.x + threadIdx.x;
  if (b > nseg) return;
  if (b == nseg) { seg_start[b] = n; return; }
  int lo = 0, hi = n;
  while (lo < hi) {
    int mid = (lo + hi) >> 1;
    if (batch[mid] < b) lo = mid + 1; else hi = mid;
  }
  seg_start[b] = lo;
}

// -------- Kernel 2: FUSED gate-score + online segment softmax + pooling ----
// One block per segment (grid-strided). Per 16-node tile per wave:
//   load h fp32 (reused for BOTH the bf16 MFMA A-operand and fp32 pooling),
//   score = tanh(h@W1+b1)@w2  (b2 omitted: constant shift cancels in softmax),
//   online-softmax accumulate  acc += e^{s-m} * h,  s += e^{s-m},  gm = max.
// End of segment: 16-lane reduce + 4-wave flash merge through LDS.
__global__ __launch_bounds__(256, 2) void fused_pool_kernel(
    const float* __restrict__ h, const float* __restrict__ w1,
    const float* __restrict__ b1, const float* __restrict__ w2,
    const int* __restrict__ seg_start, float* __restrict__ g, int B)
{
  __shared__ __bf16 sWt[HD * HD];   // W1^T bf16, XOR-swizzled 16B slots (32 KB)
  __shared__ float mAcc[4][HD];
  __shared__ float mGm[4][HD];
  __shared__ float mS[4];
  __shared__ float mM[4];

  // One-time stage: sWt[c][k] = W1[k][c], slot-swizzled: for row c, the 16B
  // slot index (k>>3) is XORed with (c&15)  -> conflict-free b128 reads.
  for (int i = threadIdx.x; i < HD * HD / 4; i += 256) {
    const int k = i >> 5;
    const int c4 = (i & 31) << 2;
    const float4 v = reinterpret_cast<const float4*>(w1)[i];
    const float vv[4] = {v.x, v.y, v.z, v.w};
#pragma unroll
    for (int q = 0; q < 4; ++q) {
      const int c = c4 + q;
      sWt[c * HD + ((((k >> 3) ^ (c & 15)) << 3) | (k & 7))] = (__bf16)vv[q];
    }
  }
  __syncthreads();

  const int lane = threadIdx.x & 63;
  const int wid  = threadIdx.x >> 6;
  const int lr   = lane & 15;
  const int kl   = lane >> 4;

  float w2r[8], b1r[8];
#pragma unroll
  for (int f = 0; f < 8; ++f) { w2r[f] = w2[16 * f + lr]; b1r[f] = b1[16 * f + lr]; }

  for (int b = blockIdx.x; b < B; b += gridDim.x) {
    const int s0  = seg_start[b];
    const int len = seg_start[b + 1] - s0;
    const int nt  = (len + 15) >> 4;

    float m = -FLT_MAX, s = 0.f;
    float acc[32], gm[32];
#pragma unroll
    for (int j = 0; j < 32; ++j) { acc[j] = 0.f; gm[j] = -FLT_MAX; }

    for (int t = wid; t < nt; t += 4) {
      const int nIt = t * 16 + lr;
      const bool valid = nIt < len;
      const size_t row = (size_t)s0 + (size_t)min(nIt, len - 1);  // clamp = valid row
      const float* hp = h + row * HD + 8 * kl;

      // fp32 h: lane holds features {32kt + 8kl + j}
      float hvF[32];
#pragma unroll
      for (int kt = 0; kt < 4; ++kt) {
        *reinterpret_cast<float4*>(&hvF[8 * kt])     = *reinterpret_cast<const float4*>(hp + 32 * kt);
        *reinterpret_cast<float4*>(&hvF[8 * kt + 4]) = *reinterpret_cast<const float4*>(hp + 32 * kt + 4);
      }
      bf16x8 a[4];
#pragma unroll
      for (int kt = 0; kt < 4; ++kt)
#pragma unroll
        for (int j = 0; j < 8; ++j) a[kt][j] = (__bf16)hvF[8 * kt + j];

      // Opaque zero blocks LICM from hoisting the 32 LDS B-reads into regs.
      int ob = 0;
      asm volatile("" : "+v"(ob));
      const __bf16* wp = sWt + ob;

      f32x4 macc[8];
#pragma unroll
      for (int f = 0; f < 8; ++f) macc[f] = (f32x4){0.f, 0.f, 0.f, 0.f};
#pragma unroll
      for (int kt = 0; kt < 4; ++kt) {
#pragma unroll
        for (int f = 0; f < 8; ++f) {
          const int c = 16 * f + lr;
          const bf16x8 bfr = *reinterpret_cast<const bf16x8*>(
              wp + c * HD + (((4 * kt + kl) ^ (c & 15)) << 3));
          macc[f] = __builtin_amdgcn_mfma_f32_16x16x32_bf16(a[kt], bfr, macc[f], 0, 0, 0);
        }
      }

      // tanh epilogue -> p[r] = score of node 4*kl + r (valid on all 16 lanes
      // of the kl group after the width-16 xor reduce)
      float p[4] = {0.f, 0.f, 0.f, 0.f};
#pragma unroll
      for (int f = 0; f < 8; ++f) {
#pragma unroll
        for (int r = 0; r < 4; ++r) {
          float x = macc[f][r] + b1r[f];
          float e = __expf(2.f * x);
          float th = 1.f - __fdividef(2.f, e + 1.f);
          p[r] = fmaf(th, w2r[f], p[r]);
        }
      }
#pragma unroll
      for (int r = 0; r < 4; ++r) {
        p[r] += __shfl_xor(p[r], 1, 16);
        p[r] += __shfl_xor(p[r], 2, 16);
        p[r] += __shfl_xor(p[r], 4, 16);
        p[r] += __shfl_xor(p[r], 8, 16);
      }

      // wave-uniform tile max (duplicated tail rows are real rows -> safe)
      float tmax = fmaxf(fmaxf(p[0], p[1]), fmaxf(p[2], p[3]));
      tmax = fmaxf(tmax, __shfl_xor(tmax, 16, 64));
      tmax = fmaxf(tmax, __shfl_xor(tmax, 32, 64));

      // broadcast score of node lr: it is p[lr&3] on lane group kl' = lr>>2
      const int src = (lr >> 2) << 4;
      const float q0 = __shfl(p[0], src, 64);
      const float q1 = __shfl(p[1], src, 64);
      const float q2 = __shfl(p[2], src, 64);
      const float q3 = __shfl(p[3], src, 64);
      const int rr = lr & 3;
      const float sc = rr == 0 ? q0 : (rr == 1 ? q1 : (rr == 2 ? q2 : q3));

      if (tmax > m) {                      // wave-uniform branch
        const float scale = __expf(m - tmax);
        s *= scale;
#pragma unroll
        for (int j = 0; j < 32; ++j) acc[j] *= scale;
        m = tmax;
      }
      const float w = valid ? __expf(sc - m) : 0.f;
      s += w;
#pragma unroll
      for (int j = 0; j < 32; ++j) {
        acc[j] = fmaf(hvF[j], w, acc[j]);
        gm[j] = fmaxf(gm[j], hvF[j]);      // clamped row is in-segment: no mask
      }
    }

    // reduce partials across the 16 lr lanes (features live per kl,kt,j)
#pragma unroll
    for (int off = 1; off <= 8; off <<= 1) {
      s += __shfl_xor(s, off, 16);
#pragma unroll
      for (int j = 0; j < 32; ++j) {
        acc[j] += __shfl_xor(acc[j], off, 16);
        gm[j] = fmaxf(gm[j], __shfl_xor(gm[j], off, 16));
      }
    }

    if (lr == 0) {                          // lanes 0,16,32,48: one per kl
#pragma unroll
      for (int kt = 0; kt < 4; ++kt) {
        const int fb = 32 * kt + 8 * kl;
        float4 va; va.x = acc[8*kt+0]; va.y = acc[8*kt+1]; va.z = acc[8*kt+2]; va.w = acc[8*kt+3];
        float4 vb; vb.x = acc[8*kt+4]; vb.y = acc[8*kt+5]; vb.z = acc[8*kt+6]; vb.w = acc[8*kt+7];
        *reinterpret_cast<float4*>(&mAcc[wid][fb])     = va;
        *reinterpret_cast<float4*>(&mAcc[wid][fb + 4]) = vb;
        float4 ma; ma.x = gm[8*kt+0]; ma.y = gm[8*kt+1]; ma.z = gm[8*kt+2]; ma.w = gm[8*kt+3];
        float4 mb; mb.x = gm[8*kt+4]; mb.y = gm[8*kt+5]; mb.z = gm[8*kt+6]; mb.w = gm[8*kt+7];
        *reinterpret_cast<float4*>(&mGm[wid][fb])     = ma;
        *reinterpret_cast<float4*>(&mGm[wid][fb + 4]) = mb;
      }
      if (kl == 0) { mS[wid] = s; mM[wid] = m; }
    }
    __syncthreads();

    if (threadIdx.x < HD) {
      const int f = threadIdx.x;
      const float M = fmaxf(fmaxf(mM[0], mM[1]), fmaxf(mM[2], mM[3]));
      float S = 0.f, ga = 0.f, gx = -FLT_MAX;
#pragma unroll
      for (int w_ = 0; w_ < 4; ++w_) {
        const float fw = __expf(mM[w_] - M);
        S  += fw * mS[w_];
        ga += fw * mAcc[w_][f];
        gx = fmaxf(gx, mGm[w_][f]);
      }
      g[(size_t)b * 256 + f]       = (S > 0.f) ? ga / S : 0.f;
      g[(size_t)b * 256 + 128 + f] = gx;
    }
    __syncthreads();   // protect merge buffers before next segment
  }
}

// -------- Kernel 3: MLP head, 4 segments per block --------
__global__ __launch_bounds__(512) void mlp_kernel(
    const float* __restrict__ g, const float* __restrict__ w1,
    const float* __restrict__ b1, const float* __restrict__ w2,
    const float* __restrict__ b2, float* __restrict__ out)
{
  __shared__ float sg[4][256];
  __shared__ float sred[4][2];
  const int t = threadIdx.x;
  const int sidx = t >> 7;
  const int u = t & 127;
  const int b0 = blockIdx.x * 4;
  sg[sidx][u]       = g[(size_t)(b0 + sidx) * 256 + u];
  sg[sidx][u + 128] = g[(size_t)(b0 + sidx) * 256 + 128 + u];
  __syncthreads();
  float acc = b1[u];
#pragma unroll 8
  for (int k = 0; k < 256; ++k)
    acc = fmaf(sg[sidx][k], w1[k * HD + u], acc);
  float v = fmaxf(acc, 0.f) * w2[u];
#pragma unroll
  for (int off = 32; off >= 1; off >>= 1) v += __shfl_xor(v, off, 64);
  if ((t & 63) == 0) sred[sidx][(t >> 6) & 1] = v;
  __syncthreads();
  if (u == 0) out[b0 + sidx] = sred[sidx][0] + sred[sidx][1] + b2[0];
}

extern "C" void kernel_launch(void* const* d_in, const int* in_sizes, int n_in,
                              void* d_out, int out_size, void* d_ws, size_t ws_size,
                              hipStream_t stream) {
  const float* h       = (const float*)d_in[0];
  const int*   batch   = (const int*)d_in[1];
  const float* gate_w1 = (const float*)d_in[2];
  const float* gate_b1 = (const float*)d_in[3];
  const float* gate_w2 = (const float*)d_in[4];
  const float* mlp_w1  = (const float*)d_in[6];
  const float* mlp_b1  = (const float*)d_in[7];
  const float* mlp_w2  = (const float*)d_in[8];
  const float* mlp_b2  = (const float*)d_in[9];
  float* out = (float*)d_out;

  const int N = in_sizes[0] / HD;   // 1048576
  const int B = out_size;           // 4096

  char* ws = (char*)d_ws;
  float* g   = (float*)ws;                              // B*256 floats
  int*   seg = (int*)(ws + (size_t)B * 256 * 4);        // B+1 ints

  seg_bounds_kernel<<<(B + 256) / 256, 256, 0, stream>>>(batch, N, B, seg);
  fused_pool_kernel<<<512, 256, 0, stream>>>(h, gate_w1, gate_b1, gate_w2,
                                             seg, g, B);
  mlp_kernel<<<B / 4, 512, 0, stream>>>(g, mlp_w1, mlp_b1, mlp_w2, mlp_b2, out);
}

// Round 5
// 182.702 us; speedup vs baseline: 3.7487x; 1.3199x over previous
//
#include <hip/hip_runtime.h>
#include <hip/hip_bf16.h>
#include <cfloat>

#define HD 128

typedef float f32x4 __attribute__((ext_vector_type(4)));
typedef __bf16 bf16x8 __attribute__((ext_vector_type(8)));

// -------- Kernel 1: segment bounds (batch is sorted) --------
__global__ void seg_bounds_kernel(const int* __restrict__ batch, int n, int nseg,
                                  int* __restrict__ seg_start) {
  int b = blockIdx.x * blockDim.x + threadIdx.x;
  if (b > nseg) return;
  if (b == nseg) { seg_start[b] = n; return; }
  int lo = 0, hi = n;
  while (lo < hi) {
    int mid = (lo + hi) >> 1;
    if (batch[mid] < b) lo = mid + 1; else hi = mid;
  }
  seg_start[b] = lo;
}

// -------- Kernel 2: FUSED gate-score + online softmax + pooling ------------
// ONE WAVE PER SEGMENT (no intra-segment barriers, no cross-wave merge).
// Per 16-node tile: h fp32 loads feed BOTH the bf16 MFMA A-operand and the
// fp32 pooling accumulators. Double-buffered prefetch (hA/hB) hides HBM
// latency under MFMA+epilogue of the previous tile.
// Score algebra: score = sum(tanh(x)*w2) = sumW2 - 2*sum(w2/(1+e^{2x}))
// (gate_b2 omitted: constant shift cancels in softmax).

#define LOAD_TILE(BUF, T)                                                   \
  {                                                                         \
    const int nIt_ = (T) * 16 + lr;                                         \
    const size_t row_ = (size_t)s0 + (size_t)min(nIt_, len - 1);            \
    const float* hp_ = h + row_ * HD + 8 * kl;                              \
    _Pragma("unroll")                                                       \
    for (int kt = 0; kt < 4; ++kt) {                                        \
      *reinterpret_cast<float4*>(&BUF[8 * kt]) =                            \
          *reinterpret_cast<const float4*>(hp_ + 32 * kt);                  \
      *reinterpret_cast<float4*>(&BUF[8 * kt + 4]) =                        \
          *reinterpret_cast<const float4*>(hp_ + 32 * kt + 4);              \
    }                                                                       \
  }

#define PROC_TILE(BUF, T)                                                   \
  {                                                                         \
    const bool valid_ = ((T) * 16 + lr) < len;                              \
    bf16x8 a_[4];                                                           \
    _Pragma("unroll")                                                       \
    for (int kt = 0; kt < 4; ++kt)                                          \
      _Pragma("unroll")                                                     \
      for (int j = 0; j < 8; ++j) a_[kt][j] = (__bf16)BUF[8 * kt + j];      \
    int ob_ = 0;                                                            \
    asm volatile("" : "+v"(ob_));                                           \
    const __bf16* wp_ = sWt + ob_;                                          \
    f32x4 macc_[8];                                                         \
    _Pragma("unroll")                                                       \
    for (int f = 0; f < 8; ++f) macc_[f] = (f32x4){0.f, 0.f, 0.f, 0.f};     \
    _Pragma("unroll")                                                       \
    for (int kt = 0; kt < 4; ++kt) {                                        \
      _Pragma("unroll")                                                     \
      for (int f = 0; f < 8; ++f) {                                         \
        const int c_ = 16 * f + lr;                                         \
        const bf16x8 bfr_ = *reinterpret_cast<const bf16x8*>(               \
            wp_ + c_ * HD + (((4 * kt + kl) ^ (c_ & 15)) << 3));            \
        macc_[f] =                                                          \
            __builtin_amdgcn_mfma_f32_16x16x32_bf16(a_[kt], bfr_, macc_[f], \
                                                    0, 0, 0);               \
      }                                                                     \
    }                                                                       \
    float p2_[4] = {0.f, 0.f, 0.f, 0.f};                                    \
    _Pragma("unroll")                                                       \
    for (int f = 0; f < 8; ++f) {                                           \
      _Pragma("unroll")                                                     \
      for (int r = 0; r < 4; ++r) {                                         \
        const float xe_ = fmaf(LOG2E2, macc_[f][r], b1s[f]);                \
        const float e_ = exp2f(xe_);                                        \
        const float t_ = __builtin_amdgcn_rcpf(1.f + e_);                   \
        p2_[r] = fmaf(t_, w2r[f], p2_[r]);                                  \
      }                                                                     \
    }                                                                       \
    _Pragma("unroll")                                                       \
    for (int r = 0; r < 4; ++r) {                                           \
      p2_[r] += __shfl_xor(p2_[r], 1, 16);                                  \
      p2_[r] += __shfl_xor(p2_[r], 2, 16);                                  \
      p2_[r] += __shfl_xor(p2_[r], 4, 16);                                  \
      p2_[r] += __shfl_xor(p2_[r], 8, 16);                                  \
    }                                                                       \
    const float minp_ = fminf(fminf(p2_[0], p2_[1]), fminf(p2_[2], p2_[3]));\
    float tmax_ = fmaf(-2.f, minp_, sumW2);                                 \
    tmax_ = fmaxf(tmax_, __shfl_xor(tmax_, 16, 64));                        \
    tmax_ = fmaxf(tmax_, __shfl_xor(tmax_, 32, 64));                        \
    const int rr_ = lr & 3;                                                 \
    const float psel_ =                                                     \
        rr_ == 0 ? p2_[0] : (rr_ == 1 ? p2_[1] : (rr_ == 2 ? p2_[2]         \
                                                            : p2_[3]));     \
    const float vsc_ = fmaf(-2.f, psel_, sumW2);                            \
    const float sc_ = __shfl(vsc_, ((lr >> 2) << 4) | (lr & 3), 64);        \
    if (tmax_ > m) {                                                        \
      const float scl_ = exp2f((m - tmax_) * LOG2E);                        \
      s *= scl_;                                                            \
      _Pragma("unroll")                                                     \
      for (int j = 0; j < 32; ++j) acc[j] *= scl_;                          \
      m = tmax_;                                                            \
    }                                                                       \
    const float w_ = valid_ ? exp2f((sc_ - m) * LOG2E) : 0.f;               \
    s += w_;                                                                \
    _Pragma("unroll")                                                       \
    for (int j = 0; j < 32; ++j) {                                          \
      acc[j] = fmaf(BUF[j], w_, acc[j]);                                    \
      gm[j] = fmaxf(gm[j], BUF[j]);                                         \
    }                                                                       \
  }

__global__ __launch_bounds__(256, 2) void fused_pool_kernel(
    const float* __restrict__ h, const float* __restrict__ w1,
    const float* __restrict__ b1, const float* __restrict__ w2,
    const int* __restrict__ seg_start, float* __restrict__ g, int B)
{
  __shared__ __bf16 sWt[HD * HD];  // W1^T bf16, XOR-swizzled 16B slots (32 KB)

  for (int i = threadIdx.x; i < HD * HD / 4; i += 256) {
    const int k = i >> 5;
    const int c4 = (i & 31) << 2;
    const float4 v = reinterpret_cast<const float4*>(w1)[i];
    const float vv[4] = {v.x, v.y, v.z, v.w};
#pragma unroll
    for (int q = 0; q < 4; ++q) {
      const int c = c4 + q;
      sWt[c * HD + ((((k >> 3) ^ (c & 15)) << 3) | (k & 7))] = (__bf16)vv[q];
    }
  }
  __syncthreads();

  const float LOG2E  = 1.44269504088896341f;
  const float LOG2E2 = 2.88539008177792681f;

  const int lane = threadIdx.x & 63;
  const int wid  = threadIdx.x >> 6;
  const int lr   = lane & 15;
  const int kl   = lane >> 4;

  float w2r[8], b1s[8];
#pragma unroll
  for (int f = 0; f < 8; ++f) {
    w2r[f] = w2[16 * f + lr];
    b1s[f] = LOG2E2 * b1[16 * f + lr];
  }
  // sumW2 = sum over all 128 cols (cols depend only on lr -> 16-lane reduce)
  float sumW2 = 0.f;
#pragma unroll
  for (int f = 0; f < 8; ++f) sumW2 += w2r[f];
  sumW2 += __shfl_xor(sumW2, 1, 16);
  sumW2 += __shfl_xor(sumW2, 2, 16);
  sumW2 += __shfl_xor(sumW2, 4, 16);
  sumW2 += __shfl_xor(sumW2, 8, 16);

  const int segStride = gridDim.x * 4;
  for (int b = blockIdx.x * 4 + wid; b < B; b += segStride) {
    const int s0  = seg_start[b];
    const int len = seg_start[b + 1] - s0;
    const int nt  = (len + 15) >> 4;

    float m = -FLT_MAX, s = 0.f;
    float acc[32], gm[32];
#pragma unroll
    for (int j = 0; j < 32; ++j) { acc[j] = 0.f; gm[j] = -FLT_MAX; }

    if (nt > 0) {
      float hA[32], hB[32];
      LOAD_TILE(hA, 0)
      int t = 0;
      for (; t + 1 < nt; t += 2) {
        LOAD_TILE(hB, t + 1)
        PROC_TILE(hA, t)
        if (t + 2 < nt) LOAD_TILE(hA, t + 2)
        PROC_TILE(hB, t + 1)
      }
      if (t < nt) PROC_TILE(hA, t)
    }

    // reduce partials across the 16 lr lanes (features depend only on kl)
#pragma unroll
    for (int off = 1; off <= 8; off <<= 1) {
      s += __shfl_xor(s, off, 16);
#pragma unroll
      for (int j = 0; j < 32; ++j) {
        acc[j] += __shfl_xor(acc[j], off, 16);
        gm[j] = fmaxf(gm[j], __shfl_xor(gm[j], off, 16));
      }
    }

    if (lr == 0) {  // lanes 0,16,32,48: one per kl group
      const float invS = (s > 0.f) ? 1.f / s : 0.f;
#pragma unroll
      for (int kt = 0; kt < 4; ++kt) {
        const int fb = 32 * kt + 8 * kl;
        float4 va, vb, ma, mb;
        va.x = acc[8*kt+0]*invS; va.y = acc[8*kt+1]*invS;
        va.z = acc[8*kt+2]*invS; va.w = acc[8*kt+3]*invS;
        vb.x = acc[8*kt+4]*invS; vb.y = acc[8*kt+5]*invS;
        vb.z = acc[8*kt+6]*invS; vb.w = acc[8*kt+7]*invS;
        ma.x = gm[8*kt+0]; ma.y = gm[8*kt+1]; ma.z = gm[8*kt+2]; ma.w = gm[8*kt+3];
        mb.x = gm[8*kt+4]; mb.y = gm[8*kt+5]; mb.z = gm[8*kt+6]; mb.w = gm[8*kt+7];
        *reinterpret_cast<float4*>(&g[(size_t)b * 256 + fb])       = va;
        *reinterpret_cast<float4*>(&g[(size_t)b * 256 + fb + 4])   = vb;
        *reinterpret_cast<float4*>(&g[(size_t)b * 256 + 128 + fb]) = ma;
        *reinterpret_cast<float4*>(&g[(size_t)b * 256 + 128 + fb + 4]) = mb;
      }
    }
  }
}

// -------- Kernel 3: MLP head, 4 segments per block --------
__global__ __launch_bounds__(512) void mlp_kernel(
    const float* __restrict__ g, const float* __restrict__ w1,
    const float* __restrict__ b1, const float* __restrict__ w2,
    const float* __restrict__ b2, float* __restrict__ out)
{
  __shared__ float sg[4][256];
  __shared__ float sred[4][2];
  const int t = threadIdx.x;
  const int sidx = t >> 7;
  const int u = t & 127;
  const int b0 = blockIdx.x * 4;
  sg[sidx][u]       = g[(size_t)(b0 + sidx) * 256 + u];
  sg[sidx][u + 128] = g[(size_t)(b0 + sidx) * 256 + 128 + u];
  __syncthreads();
  float acc = b1[u];
#pragma unroll 8
  for (int k = 0; k < 256; ++k)
    acc = fmaf(sg[sidx][k], w1[k * HD + u], acc);
  float v = fmaxf(acc, 0.f) * w2[u];
#pragma unroll
  for (int off = 32; off >= 1; off >>= 1) v += __shfl_xor(v, off, 64);
  if ((t & 63) == 0) sred[sidx][(t >> 6) & 1] = v;
  __syncthreads();
  if (u == 0) out[b0 + sidx] = sred[sidx][0] + sred[sidx][1] + b2[0];
}

extern "C" void kernel_launch(void* const* d_in, const int* in_sizes, int n_in,
                              void* d_out, int out_size, void* d_ws, size_t ws_size,
                              hipStream_t stream) {
  const float* h       = (const float*)d_in[0];
  const int*   batch   = (const int*)d_in[1];
  const float* gate_w1 = (const float*)d_in[2];
  const float* gate_b1 = (const float*)d_in[3];
  const float* gate_w2 = (const float*)d_in[4];
  const float* mlp_w1  = (const float*)d_in[6];
  const float* mlp_b1  = (const float*)d_in[7];
  const float* mlp_w2  = (const float*)d_in[8];
  const float* mlp_b2  = (const float*)d_in[9];
  float* out = (float*)d_out;

  const int N = in_sizes[0] / HD;   // 1048576
  const int B = out_size;           // 4096

  char* ws = (char*)d_ws;
  float* g   = (float*)ws;                              // B*256 floats
  int*   seg = (int*)(ws + (size_t)B * 256 * 4);        // B+1 ints

  seg_bounds_kernel<<<(B + 256) / 256, 256, 0, stream>>>(batch, N, B, seg);
  // 1024 blocks x 4 waves = 4096 waves -> one segment per wave.
  fused_pool_kernel<<<1024, 256, 0, stream>>>(h, gate_w1, gate_b1, gate_w2,
                                              seg, g, B);
  mlp_kernel<<<B / 4, 512, 0, stream>>>(g, mlp_w1, mlp_b1, mlp_w2, mlp_b2, out);
}